// Round 18
// baseline (71.580 us; speedup 1.0000x reference)
//
#include <hip/hip_runtime.h>

// BinaryLinear int8 path (round 18):
//   prep    : fused {X f32 -> i8 per-row quant + Sc} and {W -> {0,1} i8, NxK}
//   gemm_bd : r8's exact 256x256 / 8-wave / BK=128 kernel (39.6us baseline)
//             with ONE change: B fragments bypass LDS -> loaded direct from
//             global (L2-resident Wt) into registers, prefetched one tile
//             ahead under the MFMA clusters. Moves B traffic from the
//             saturated LDS port to the idle VMEM/L1 port. A unchanged
//             (gload_lds + XOR swizzle, 64KB dbuf).
// Fallback: round-1 fused bf16 kernel if ws too small.

#define MDIM 8192
#define NDIM 2048
#define KDIM 2048
#define NT   (KDIM / 128)         // 16 K-tiles of 128 i8
#define CH   (64 * KDIM)          // chunk stride: 64 rows * 2048 B

typedef __attribute__((ext_vector_type(8))) short short8;
typedef __attribute__((ext_vector_type(4))) float float4v;
typedef __attribute__((ext_vector_type(4))) float f32x4;
typedef __attribute__((ext_vector_type(4))) int int4v;
typedef __attribute__((ext_vector_type(4))) unsigned short ushort4v;
typedef __attribute__((ext_vector_type(8))) unsigned short ushort8v;

__device__ __forceinline__ unsigned short f2bf(float f) {
    union { float f; unsigned u; } v; v.f = f;
    unsigned r = v.u + 0x7FFFu + ((v.u >> 16) & 1u);
    return (unsigned short)(r >> 16);
}

__device__ __forceinline__ void gload_lds16(void* l, const void* g) {
    __builtin_amdgcn_global_load_lds(
        (const __attribute__((address_space(1))) unsigned int*)g,
        (__attribute__((address_space(3))) unsigned int*)l,
        16, 0, 0);
}

#define FENCE asm volatile("" ::: "memory")
#define BAR do { FENCE; __builtin_amdgcn_s_barrier(); FENCE; } while (0)

// ---------------- pass 1 (fused): quantize X rows + binarize/transpose W ----
__global__ __launch_bounds__(256) void prep(const float* __restrict__ X,
                                            const float* __restrict__ W,
                                            signed char* __restrict__ Xq,
                                            signed char* __restrict__ Wt,
                                            float* __restrict__ Sc) {
    __shared__ __align__(16) signed char T[64][80];
    __shared__ float wm[4];
    const int t = threadIdx.x;
    const int bid = blockIdx.x;

    if (bid < MDIM) {
        const int row = bid;
        const float* xr = X + (size_t)row * KDIM + t * 8;
        float4v a = *reinterpret_cast<const float4v*>(xr);
        float4v b = *reinterpret_cast<const float4v*>(xr + 4);
        float m = fabsf(a[0]);
        m = fmaxf(m, fabsf(a[1])); m = fmaxf(m, fabsf(a[2])); m = fmaxf(m, fabsf(a[3]));
        m = fmaxf(m, fabsf(b[0])); m = fmaxf(m, fabsf(b[1]));
        m = fmaxf(m, fabsf(b[2])); m = fmaxf(m, fabsf(b[3]));
#pragma unroll
        for (int off = 32; off; off >>= 1)
            m = fmaxf(m, __shfl_xor(m, off));
        if ((t & 63) == 0) wm[t >> 6] = m;
        __syncthreads();
        const float s = fmaxf(fmaxf(wm[0], wm[1]), fmaxf(wm[2], wm[3]));
        const float inv = (s > 0.f) ? 127.0f / s : 0.f;

        int q[8];
        q[0] = __float2int_rn(a[0] * inv); q[1] = __float2int_rn(a[1] * inv);
        q[2] = __float2int_rn(a[2] * inv); q[3] = __float2int_rn(a[3] * inv);
        q[4] = __float2int_rn(b[0] * inv); q[5] = __float2int_rn(b[1] * inv);
        q[6] = __float2int_rn(b[2] * inv); q[7] = __float2int_rn(b[3] * inv);
        unsigned lo = (q[0] & 255) | ((q[1] & 255) << 8) | ((q[2] & 255) << 16) | ((unsigned)(q[3] & 255) << 24);
        unsigned hi = (q[4] & 255) | ((q[5] & 255) << 8) | ((q[6] & 255) << 16) | ((unsigned)(q[7] & 255) << 24);
        unsigned* dst = (unsigned*)(Xq + (size_t)row * KDIM + t * 8);
        dst[0] = lo; dst[1] = hi;
        if (t == 0) Sc[row] = s * (1.0f / 127.0f);
    } else {
        const int wb = bid - MDIM;
        const int k0 = (wb >> 5) * 64;
        const int n0 = (wb & 31) * 64;
        const int kr = t >> 4;
        const int nc = (t & 15) * 4;
#pragma unroll
        for (int rr = 0; rr < 4; ++rr) {
            int k = k0 + rr * 16 + kr;
            float4v w4 = *reinterpret_cast<const float4v*>(W + (size_t)k * NDIM + n0 + nc);
#pragma unroll
            for (int c = 0; c < 4; ++c)
                T[nc + c][rr * 16 + kr] = (w4[c] > 0.0f) ? (signed char)1 : (signed char)0;
        }
        __syncthreads();
        const int row = t >> 2, ch = t & 3;
        int4v v = *reinterpret_cast<const int4v*>(&T[row][ch * 16]);
        *reinterpret_cast<int4v*>(Wt + (size_t)(n0 + row) * KDIM + k0 + ch * 16) = v;
    }
}

// ---------------- pass 2: 256x256 i8 GEMM, A-LDS + B-direct ----------------
// A LDS per buffer (32 KB): [256 rows][128 B]; dbuf 64 KB. 16B slot s of
// row r holds global k-octet s^(r&7) (pre-swizzled source, linear dest).
// Wave w: wr=w>>2, wc=w&3; wave tile 128x64 = 8mi x 4ni, 2 ks.
// B frag (ni,ks) of tile t loaded DIRECT from global:
//   lane(fr,fg): addr = Bt[(bn*256 + wc*64 + ni*16 + fr)*K + t*128 + ks*64
//                         + fg*16]    (16 rows x 64B segments; L2-hot)
// Per tile: vmcnt(0); BAR; stage A(t+1) x4; read a01,a23; issue bfn(t+1) x8;
// MFMA01; read a45; MFMA23; read a67; MFMA45; MFMA67; bf = bfn.
__global__ __launch_bounds__(512, 1) void gemm_bd(const signed char* __restrict__ A,
                                                  const signed char* __restrict__ Bt,
                                                  const float* __restrict__ Sc,
                                                  float* __restrict__ O) {
    extern __shared__ char lds[];
    const int tid  = threadIdx.x;
    const int lane = tid & 63;
    const int w    = tid >> 6;       // 0..7
    const int wr   = w >> 2;         // 0..1
    const int wc   = w & 3;          // 0..3

    int id  = blockIdx.x;            // 256 blocks, %8==0 -> bijective
    int swz = (id & 7) * 32 + (id >> 3);
    const int bm = swz >> 3;         // 0..31
    const int bn = swz & 7;          // 0..7

    // A staging source: lane l -> row (w*8 + l>>3), pre-swizzled slot ((l&7)^(l>>3))
    const int l3 = lane >> 3, l7 = lane & 7;
    const int srcOff = (w * 8 + l3) * KDIM + ((l7 ^ l3) << 4);
    const char* gA = (const char*)A + (size_t)(bm * 256) * KDIM + srcOff;

    // fragment constants: lane l -> row l&15, 16 k-bytes at slot l>>4
    const int fr = lane & 15, fg = lane >> 4;
    const int se0 = ((fg)     ^ (fr & 7)) << 4;   // A ks0: slots 0-3
    const int se1 = ((4 + fg) ^ (fr & 7)) << 4;   // A ks1: slots 4-7
    const int aRd = (wr * 128 + fr) * 128;        // + buf + mi*2048 + se

    // B direct base: row (bn*256 + wc*64 + fr), byte fg*16
    const char* gBf = (const char*)Bt + (size_t)(bn * 256 + wc * 64 + fr) * KDIM + fg * 16;

    int4v acc[8][4];
#pragma unroll
    for (int i = 0; i < 8; ++i)
#pragma unroll
        for (int j = 0; j < 4; ++j) {
            acc[i][j][0] = 0; acc[i][j][1] = 0; acc[i][j][2] = 0; acc[i][j][3] = 0;
        }

    // prologue: stage A tile 0; load B tile 0 into regs
#pragma unroll
    for (int c = 0; c < 4; ++c)
        gload_lds16(lds + c * 8192 + w * 1024, gA + (size_t)c * CH);
    int4v bf[4][2], bfn[4][2];
#pragma unroll
    for (int ni = 0; ni < 4; ++ni)
#pragma unroll
        for (int ks = 0; ks < 2; ++ks)
            bf[ni][ks] = *reinterpret_cast<const int4v*>(
                gBf + (size_t)ni * 16 * KDIM + ks * 64);

    for (int t = 0; t < NT; ++t) {
        const int cur = (t & 1) << 15;         // A buffers: 32 KB stride
        const int nxt = ((t + 1) & 1) << 15;
        const bool more = (t + 1 < NT);
        const char* aN = gA + (size_t)(t + 1) * 128;

        // A stages of cur + B loads of tile t landed
        asm volatile("s_waitcnt vmcnt(0)" ::: "memory");
        BAR;

        // ---- stage A(t+1) ----
        if (more) {
#pragma unroll
            for (int c = 0; c < 4; ++c)
                gload_lds16(lds + nxt + c * 8192 + w * 1024, aN + (size_t)c * CH);
        }

        // ---- A frag reads (pipelined) + issue B(t+1) + MFMA clusters ----
        int4v a01[2][2], a23[2][2], a45[2][2], a67[2][2];
#pragma unroll
        for (int d = 0; d < 2; ++d) {
            a01[d][0] = *reinterpret_cast<const int4v*>(lds + cur + aRd + d * 2048 + se0);
            a01[d][1] = *reinterpret_cast<const int4v*>(lds + cur + aRd + d * 2048 + se1);
        }
#pragma unroll
        for (int d = 0; d < 2; ++d) {
            a23[d][0] = *reinterpret_cast<const int4v*>(lds + cur + aRd + (2 + d) * 2048 + se0);
            a23[d][1] = *reinterpret_cast<const int4v*>(lds + cur + aRd + (2 + d) * 2048 + se1);
        }
        if (more) {
            const char* bN = gBf + (size_t)(t + 1) * 128;
#pragma unroll
            for (int ni = 0; ni < 4; ++ni)
#pragma unroll
                for (int ks = 0; ks < 2; ++ks)
                    bfn[ni][ks] = *reinterpret_cast<const int4v*>(
                        bN + (size_t)ni * 16 * KDIM + ks * 64);
        }
        __builtin_amdgcn_s_setprio(1);
#pragma unroll
        for (int d = 0; d < 2; ++d)
#pragma unroll
            for (int ni = 0; ni < 4; ++ni) {
                acc[d][ni] = __builtin_amdgcn_mfma_i32_16x16x64_i8(a01[d][0], bf[ni][0], acc[d][ni], 0, 0, 0);
                acc[d][ni] = __builtin_amdgcn_mfma_i32_16x16x64_i8(a01[d][1], bf[ni][1], acc[d][ni], 0, 0, 0);
            }
        __builtin_amdgcn_s_setprio(0);
#pragma unroll
        for (int d = 0; d < 2; ++d) {
            a45[d][0] = *reinterpret_cast<const int4v*>(lds + cur + aRd + (4 + d) * 2048 + se0);
            a45[d][1] = *reinterpret_cast<const int4v*>(lds + cur + aRd + (4 + d) * 2048 + se1);
        }
        __builtin_amdgcn_s_setprio(1);
#pragma unroll
        for (int d = 0; d < 2; ++d)
#pragma unroll
            for (int ni = 0; ni < 4; ++ni) {
                acc[2 + d][ni] = __builtin_amdgcn_mfma_i32_16x16x64_i8(a23[d][0], bf[ni][0], acc[2 + d][ni], 0, 0, 0);
                acc[2 + d][ni] = __builtin_amdgcn_mfma_i32_16x16x64_i8(a23[d][1], bf[ni][1], acc[2 + d][ni], 0, 0, 0);
            }
        __builtin_amdgcn_s_setprio(0);
#pragma unroll
        for (int d = 0; d < 2; ++d) {
            a67[d][0] = *reinterpret_cast<const int4v*>(lds + cur + aRd + (6 + d) * 2048 + se0);
            a67[d][1] = *reinterpret_cast<const int4v*>(lds + cur + aRd + (6 + d) * 2048 + se1);
        }
        __builtin_amdgcn_s_setprio(1);
#pragma unroll
        for (int d = 0; d < 2; ++d)
#pragma unroll
            for (int ni = 0; ni < 4; ++ni) {
                acc[4 + d][ni] = __builtin_amdgcn_mfma_i32_16x16x64_i8(a45[d][0], bf[ni][0], acc[4 + d][ni], 0, 0, 0);
                acc[4 + d][ni] = __builtin_amdgcn_mfma_i32_16x16x64_i8(a45[d][1], bf[ni][1], acc[4 + d][ni], 0, 0, 0);
            }
#pragma unroll
        for (int d = 0; d < 2; ++d)
#pragma unroll
            for (int ni = 0; ni < 4; ++ni) {
                acc[6 + d][ni] = __builtin_amdgcn_mfma_i32_16x16x64_i8(a67[d][0], bf[ni][0], acc[6 + d][ni], 0, 0, 0);
                acc[6 + d][ni] = __builtin_amdgcn_mfma_i32_16x16x64_i8(a67[d][1], bf[ni][1], acc[6 + d][ni], 0, 0, 0);
            }
        __builtin_amdgcn_s_setprio(0);
        FENCE;

        // ---- rotate B registers (compiler inserts vmcnt wait for bfn) ----
        if (more) {
#pragma unroll
            for (int ni = 0; ni < 4; ++ni)
#pragma unroll
                for (int ks = 0; ks < 2; ++ks)
                    bf[ni][ks] = bfn[ni][ks];
        }
    }

    // ---- epilogue: C/D col = lane&15, row = 4*(lane>>4) + reg; dequant ----
    const int orow0 = bm * 256 + wr * 128 + fg * 4;
    const int ocol0 = bn * 256 + wc * 64 + fr;
#pragma unroll
    for (int mi = 0; mi < 8; ++mi)
#pragma unroll
        for (int r = 0; r < 4; ++r) {
            const int row = orow0 + mi * 16 + r;
            const float s = Sc[row];
            float* op = O + (size_t)row * NDIM + ocol0;
#pragma unroll
            for (int ni = 0; ni < 4; ++ni)
                op[ni * 16] = s * (float)acc[mi][ni][r];
        }
}

// ---------------- fallback: round-1 fused bf16 kernel ----------------
__global__ __launch_bounds__(256, 2) void binlin_fused(
        const float* __restrict__ X, const float* __restrict__ W,
        float* __restrict__ O) {
    const int tid = threadIdx.x;
    const int lane = tid & 63;
    const int wave = tid >> 6;
    const int wr = wave >> 1, wc = wave & 1;
    const int NWG = (MDIM / 128) * (NDIM / 128);
    int id = blockIdx.x;
    int swz = (id & 7) * (NWG >> 3) + (id >> 3);
    const int bm = swz >> 4, bn = swz & 15;

    __shared__ __align__(16) unsigned short As[128][40];
    __shared__ __align__(16) unsigned short Bs[128][40];

    const int rA = tid >> 3, kA = (tid & 7) * 4;
    const float* aPtr = X + (size_t)(bm * 128 + rA) * KDIM + kA;
    const int nB = (tid & 31) * 4, kB = (tid >> 5) * 4;
    const float* bPtr = W + (size_t)kB * NDIM + (size_t)bn * 128 + nB;

    float4v aReg[4], bReg[4];
#pragma unroll
    for (int p = 0; p < 4; ++p)
        aReg[p] = *reinterpret_cast<const float4v*>(aPtr + (size_t)(32 * p) * KDIM);
#pragma unroll
    for (int dk = 0; dk < 4; ++dk)
        bReg[dk] = *reinterpret_cast<const float4v*>(bPtr + (size_t)dk * NDIM);

    f32x4 acc[4][4];
#pragma unroll
    for (int i = 0; i < 4; ++i)
#pragma unroll
        for (int j = 0; j < 4; ++j) {
            acc[i][j][0] = 0.f; acc[i][j][1] = 0.f; acc[i][j][2] = 0.f; acc[i][j][3] = 0.f;
        }

    const int r16 = lane & 15, g8 = (lane >> 4) * 8;
    for (int kt = 0; kt < KDIM; kt += 32) {
#pragma unroll
        for (int p = 0; p < 4; ++p) {
            ushort4v v;
            v[0] = f2bf(aReg[p][0]); v[1] = f2bf(aReg[p][1]);
            v[2] = f2bf(aReg[p][2]); v[3] = f2bf(aReg[p][3]);
            *reinterpret_cast<ushort4v*>(&As[rA + 32 * p][kA]) = v;
        }
        unsigned short bb[4][4];
#pragma unroll
        for (int dk = 0; dk < 4; ++dk)
#pragma unroll
            for (int dn = 0; dn < 4; ++dn)
                bb[dn][dk] = (bReg[dk][dn] > 0.0f) ? (unsigned short)0x3F80u
                                                   : (unsigned short)0u;
#pragma unroll
        for (int dn = 0; dn < 4; ++dn) {
            ushort4v v;
            v[0] = bb[dn][0]; v[1] = bb[dn][1]; v[2] = bb[dn][2]; v[3] = bb[dn][3];
            *reinterpret_cast<ushort4v*>(&Bs[nB + dn][kB]) = v;
        }
        __syncthreads();
        if (kt + 32 < KDIM) {
#pragma unroll
            for (int p = 0; p < 4; ++p)
                aReg[p] = *reinterpret_cast<const float4v*>(
                    aPtr + (size_t)(32 * p) * KDIM + (kt + 32));
#pragma unroll
            for (int dk = 0; dk < 4; ++dk)
                bReg[dk] = *reinterpret_cast<const float4v*>(
                    bPtr + (size_t)(kt + 32 + dk) * NDIM);
        }
        short8 af[4], bfv[4];
#pragma unroll
        for (int mi = 0; mi < 4; ++mi)
            af[mi] = *reinterpret_cast<const short8*>(&As[wr * 64 + mi * 16 + r16][g8]);
#pragma unroll
        for (int ni = 0; ni < 4; ++ni)
            bfv[ni] = *reinterpret_cast<const short8*>(&Bs[wc * 64 + ni * 16 + r16][g8]);
#pragma unroll
        for (int mi = 0; mi < 4; ++mi)
#pragma unroll
            for (int ni = 0; ni < 4; ++ni)
                acc[mi][ni] = __builtin_amdgcn_mfma_f32_16x16x32_bf16(
                    af[mi], bfv[ni], acc[mi][ni], 0, 0, 0);
        __syncthreads();
    }

    const int orow0 = bm * 128 + wr * 64 + (lane >> 4) * 4;
    const int ocol0 = bn * 128 + wc * 64 + r16;
#pragma unroll
    for (int mi = 0; mi < 4; ++mi)
#pragma unroll
        for (int ni = 0; ni < 4; ++ni)
#pragma unroll
            for (int r = 0; r < 4; ++r)
                O[(size_t)(orow0 + mi * 16 + r) * NDIM + ocol0 + ni * 16] =
                    acc[mi][ni][r];
}

extern "C" void kernel_launch(void* const* d_in, const int* in_sizes, int n_in,
                              void* d_out, int out_size, void* d_ws, size_t ws_size,
                              hipStream_t stream) {
    const float* X = (const float*)d_in[0];
    const float* W = (const float*)d_in[1];
    float* O = (float*)d_out;
    (void)in_sizes; (void)n_in; (void)out_size;

    const size_t xq_bytes = (size_t)MDIM * KDIM;          // 16 MB
    const size_t wt_bytes = (size_t)NDIM * KDIM;          // 4 MB
    const size_t sc_bytes = (size_t)MDIM * sizeof(float); // 32 KB
    const size_t need = xq_bytes + wt_bytes + sc_bytes;

    if (ws_size >= need) {
        signed char* Xq = (signed char*)d_ws;
        signed char* Wt = Xq + xq_bytes;
        float* Sc = (float*)(Wt + wt_bytes);
        hipFuncSetAttribute((const void*)gemm_bd,
                            hipFuncAttributeMaxDynamicSharedMemorySize, 65536);
        prep<<<dim3(MDIM + (KDIM / 64) * (NDIM / 64)), dim3(256), 0, stream>>>(X, W, Xq, Wt, Sc);
        gemm_bd<<<dim3((MDIM / 256) * (NDIM / 256)), dim3(512), 65536, stream>>>(Xq, Wt, Sc, O);
    } else {
        binlin_fused<<<dim3((MDIM / 128) * (NDIM / 128)), dim3(256), 0, stream>>>(X, W, O);
    }
}

// Round 19
// 55.685 us; speedup vs baseline: 1.2854x; 1.2854x over previous
//
#include <hip/hip_runtime.h>

// BinaryLinear int8 path (FINAL — revert to round-13 best, 55.57 us):
//   prep   : fused {X f32 -> i8 per-row quant + Sc} and {W -> {0,1} i8, NxK}
//   gemm_mb: 256x256 tile, 1024 threads = 16 waves (4x4, wave tile 64x64),
//            BK=128, dbuf 128KB LDS, 1-barrier+1-vmcnt(0) loop, XOR swizzle
//            (0 bank conflicts), mfma_i32_16x16x64_i8, f32 dequant epilogue.
// 13 schedule families bracket the GEMM at 40+-3 us = 44% of the measured
// i8 MFMA ceiling at this K=2048 shape; prep is at its HBM BW floor.
// Fallback: round-1 fused bf16 kernel if ws too small.

#define MDIM 8192
#define NDIM 2048
#define KDIM 2048
#define NT   (KDIM / 128)         // 16 K-tiles of 128 i8

typedef __attribute__((ext_vector_type(8))) short short8;
typedef __attribute__((ext_vector_type(4))) float float4v;
typedef __attribute__((ext_vector_type(4))) float f32x4;
typedef __attribute__((ext_vector_type(4))) int int4v;
typedef __attribute__((ext_vector_type(4))) unsigned short ushort4v;
typedef __attribute__((ext_vector_type(8))) unsigned short ushort8v;

__device__ __forceinline__ unsigned short f2bf(float f) {
    union { float f; unsigned u; } v; v.f = f;
    unsigned r = v.u + 0x7FFFu + ((v.u >> 16) & 1u);
    return (unsigned short)(r >> 16);
}

__device__ __forceinline__ void gload_lds16(void* l, const void* g) {
    __builtin_amdgcn_global_load_lds(
        (const __attribute__((address_space(1))) unsigned int*)g,
        (__attribute__((address_space(3))) unsigned int*)l,
        16, 0, 0);
}

#define FENCE asm volatile("" ::: "memory")
#define BAR do { FENCE; __builtin_amdgcn_s_barrier(); FENCE; } while (0)

// ---------------- pass 1 (fused): quantize X rows + binarize/transpose W ----
__global__ __launch_bounds__(256) void prep(const float* __restrict__ X,
                                            const float* __restrict__ W,
                                            signed char* __restrict__ Xq,
                                            signed char* __restrict__ Wt,
                                            float* __restrict__ Sc) {
    __shared__ __align__(16) signed char T[64][80];
    __shared__ float wm[4];
    const int t = threadIdx.x;
    const int bid = blockIdx.x;

    if (bid < MDIM) {
        const int row = bid;
        const float* xr = X + (size_t)row * KDIM + t * 8;
        float4v a = *reinterpret_cast<const float4v*>(xr);
        float4v b = *reinterpret_cast<const float4v*>(xr + 4);
        float m = fabsf(a[0]);
        m = fmaxf(m, fabsf(a[1])); m = fmaxf(m, fabsf(a[2])); m = fmaxf(m, fabsf(a[3]));
        m = fmaxf(m, fabsf(b[0])); m = fmaxf(m, fabsf(b[1]));
        m = fmaxf(m, fabsf(b[2])); m = fmaxf(m, fabsf(b[3]));
#pragma unroll
        for (int off = 32; off; off >>= 1)
            m = fmaxf(m, __shfl_xor(m, off));
        if ((t & 63) == 0) wm[t >> 6] = m;
        __syncthreads();
        const float s = fmaxf(fmaxf(wm[0], wm[1]), fmaxf(wm[2], wm[3]));
        const float inv = (s > 0.f) ? 127.0f / s : 0.f;

        int q[8];
        q[0] = __float2int_rn(a[0] * inv); q[1] = __float2int_rn(a[1] * inv);
        q[2] = __float2int_rn(a[2] * inv); q[3] = __float2int_rn(a[3] * inv);
        q[4] = __float2int_rn(b[0] * inv); q[5] = __float2int_rn(b[1] * inv);
        q[6] = __float2int_rn(b[2] * inv); q[7] = __float2int_rn(b[3] * inv);
        unsigned lo = (q[0] & 255) | ((q[1] & 255) << 8) | ((q[2] & 255) << 16) | ((unsigned)(q[3] & 255) << 24);
        unsigned hi = (q[4] & 255) | ((q[5] & 255) << 8) | ((q[6] & 255) << 16) | ((unsigned)(q[7] & 255) << 24);
        unsigned* dst = (unsigned*)(Xq + (size_t)row * KDIM + t * 8);
        dst[0] = lo; dst[1] = hi;
        if (t == 0) Sc[row] = s * (1.0f / 127.0f);
    } else {
        const int wb = bid - MDIM;
        const int k0 = (wb >> 5) * 64;
        const int n0 = (wb & 31) * 64;
        const int kr = t >> 4;
        const int nc = (t & 15) * 4;
#pragma unroll
        for (int rr = 0; rr < 4; ++rr) {
            int k = k0 + rr * 16 + kr;
            float4v w4 = *reinterpret_cast<const float4v*>(W + (size_t)k * NDIM + n0 + nc);
#pragma unroll
            for (int c = 0; c < 4; ++c)
                T[nc + c][rr * 16 + kr] = (w4[c] > 0.0f) ? (signed char)1 : (signed char)0;
        }
        __syncthreads();
        const int row = t >> 2, ch = t & 3;
        int4v v = *reinterpret_cast<const int4v*>(&T[row][ch * 16]);
        *reinterpret_cast<int4v*>(Wt + (size_t)(n0 + row) * KDIM + k0 + ch * 16) = v;
    }
}

// ---------------- pass 2: 256x256 i8 GEMM, 1024-thr mega-block ----------------
// LDS per buffer (64 KB): A [256 rows][128 B] at +0, B at +32768; 16B slot s
// of row r holds global k-octet s^(r&7) (via pre-swizzled source; dest
// linear). Wave w: wr=w>>2 (0..3), wc=w&3 (0..3); wave tile 64x64 =
// 4mi x 4ni 16x16x64 frags, 2 ks per 128-B tile.
// Stage per wave: 2 A instrs (rows w*16 + {0..7}/{8..15}) + 2 B instrs.
// Per tile: vmcnt(0) [loads issued one tile ago]; BAR; stage 4 into nxt;
// read ks0 (8 b128); 16 MFMA; read ks1; 16 MFMA (setprio).
__global__ __launch_bounds__(1024, 4) void gemm_mb(const signed char* __restrict__ A,
                                                   const signed char* __restrict__ Bt,
                                                   const float* __restrict__ Sc,
                                                   float* __restrict__ O) {
    extern __shared__ char lds[];
    const int tid  = threadIdx.x;
    const int lane = tid & 63;
    const int w    = tid >> 6;       // 0..15
    const int wr   = w >> 2;         // 0..3
    const int wc   = w & 3;          // 0..3

    int id  = blockIdx.x;            // 256 blocks, %8==0 -> bijective
    int swz = (id & 7) * 32 + (id >> 3);
    const int bm = swz >> 3;         // 0..31
    const int bn = swz & 7;          // 0..7

    // staging source: lane l -> row (l>>3), pre-swizzled slot ((l&7)^(l>>3 &7))
    const int l3 = lane >> 3, l7 = lane & 7;
    const int srcOff = (w * 16 + l3) * KDIM + ((l7 ^ l3) << 4);   // rows w*16 + l3 (+8 for 2nd instr)
    const char* gA = (const char*)A + (size_t)(bm * 256) * KDIM + srcOff;
    const char* gB = (const char*)Bt + (size_t)(bn * 256) * KDIM + srcOff;

    // fragment read constants: lane l -> row l&15, 16 k-bytes at slot l>>4
    const int fr = lane & 15, fg = lane >> 4;
    const int se0 = ((fg)     ^ (fr & 7)) << 4;   // ks0: slots 0-3
    const int se1 = ((4 + fg) ^ (fr & 7)) << 4;   // ks1: slots 4-7
    const int aRd = (wr * 64 + fr) * 128;         // + buf + mi*2048 + se
    const int bRd = 32768 + (wc * 64 + fr) * 128; // + buf + ni*2048 + se

    int4v acc[4][4];
#pragma unroll
    for (int i = 0; i < 4; ++i)
#pragma unroll
        for (int j = 0; j < 4; ++j) {
            acc[i][j][0] = 0; acc[i][j][1] = 0; acc[i][j][2] = 0; acc[i][j][3] = 0;
        }

    // prologue: stage tile 0 into buf 0 (wave w stages its own 16 A-rows + 16 B-rows)
    gload_lds16(lds + w * 2048,              gA);
    gload_lds16(lds + w * 2048 + 1024,       gA + (size_t)8 * KDIM);
    gload_lds16(lds + 32768 + w * 2048,      gB);
    gload_lds16(lds + 32768 + w * 2048 + 1024, gB + (size_t)8 * KDIM);

    for (int t = 0; t < NT; ++t) {
        const int cur = (t & 1) << 16;
        const int nxt = ((t + 1) & 1) << 16;
        const bool more = (t + 1 < NT);
        const char* gAs = gA + (size_t)(t + 1) * 128;
        const char* gBs = gB + (size_t)(t + 1) * 128;

        // own staged loads for buffer cur landed (issued a full tile ago)
        asm volatile("s_waitcnt vmcnt(0)" ::: "memory");
        BAR;

        // ---- stage tile t+1 into nxt ----
        if (more) {
            gload_lds16(lds + nxt + w * 2048,                gAs);
            gload_lds16(lds + nxt + w * 2048 + 1024,         gAs + (size_t)8 * KDIM);
            gload_lds16(lds + nxt + 32768 + w * 2048,        gBs);
            gload_lds16(lds + nxt + 32768 + w * 2048 + 1024, gBs + (size_t)8 * KDIM);
        }

        // ---- ks0: read 8 frags + 16 MFMA ----
        int4v af[4], bf[4];
#pragma unroll
        for (int mi = 0; mi < 4; ++mi)
            af[mi] = *reinterpret_cast<const int4v*>(lds + cur + aRd + mi * 2048 + se0);
#pragma unroll
        for (int ni = 0; ni < 4; ++ni)
            bf[ni] = *reinterpret_cast<const int4v*>(lds + cur + bRd + ni * 2048 + se0);
        __builtin_amdgcn_s_setprio(1);
#pragma unroll
        for (int mi = 0; mi < 4; ++mi)
#pragma unroll
            for (int ni = 0; ni < 4; ++ni)
                acc[mi][ni] = __builtin_amdgcn_mfma_i32_16x16x64_i8(
                    af[mi], bf[ni], acc[mi][ni], 0, 0, 0);
        __builtin_amdgcn_s_setprio(0);

        // ---- ks1: read 8 frags + 16 MFMA ----
#pragma unroll
        for (int mi = 0; mi < 4; ++mi)
            af[mi] = *reinterpret_cast<const int4v*>(lds + cur + aRd + mi * 2048 + se1);
#pragma unroll
        for (int ni = 0; ni < 4; ++ni)
            bf[ni] = *reinterpret_cast<const int4v*>(lds + cur + bRd + ni * 2048 + se1);
        __builtin_amdgcn_s_setprio(1);
#pragma unroll
        for (int mi = 0; mi < 4; ++mi)
#pragma unroll
            for (int ni = 0; ni < 4; ++ni)
                acc[mi][ni] = __builtin_amdgcn_mfma_i32_16x16x64_i8(
                    af[mi], bf[ni], acc[mi][ni], 0, 0, 0);
        __builtin_amdgcn_s_setprio(0);
        FENCE;
    }

    // ---- epilogue: C/D col = lane&15, row = 4*(lane>>4) + reg; dequant ----
    const int orow0 = bm * 256 + wr * 64 + fg * 4;
    const int ocol0 = bn * 256 + wc * 64 + fr;
#pragma unroll
    for (int mi = 0; mi < 4; ++mi)
#pragma unroll
        for (int r = 0; r < 4; ++r) {
            const int row = orow0 + mi * 16 + r;
            const float s = Sc[row];
            float* op = O + (size_t)row * NDIM + ocol0;
#pragma unroll
            for (int ni = 0; ni < 4; ++ni)
                op[ni * 16] = s * (float)acc[mi][ni][r];
        }
}

// ---------------- fallback: round-1 fused bf16 kernel ----------------
__global__ __launch_bounds__(256, 2) void binlin_fused(
        const float* __restrict__ X, const float* __restrict__ W,
        float* __restrict__ O) {
    const int tid = threadIdx.x;
    const int lane = tid & 63;
    const int wave = tid >> 6;
    const int wr = wave >> 1, wc = wave & 1;
    const int NWG = (MDIM / 128) * (NDIM / 128);
    int id = blockIdx.x;
    int swz = (id & 7) * (NWG >> 3) + (id >> 3);
    const int bm = swz >> 4, bn = swz & 15;

    __shared__ __align__(16) unsigned short As[128][40];
    __shared__ __align__(16) unsigned short Bs[128][40];

    const int rA = tid >> 3, kA = (tid & 7) * 4;
    const float* aPtr = X + (size_t)(bm * 128 + rA) * KDIM + kA;
    const int nB = (tid & 31) * 4, kB = (tid >> 5) * 4;
    const float* bPtr = W + (size_t)kB * NDIM + (size_t)bn * 128 + nB;

    float4v aReg[4], bReg[4];
#pragma unroll
    for (int p = 0; p < 4; ++p)
        aReg[p] = *reinterpret_cast<const float4v*>(aPtr + (size_t)(32 * p) * KDIM);
#pragma unroll
    for (int dk = 0; dk < 4; ++dk)
        bReg[dk] = *reinterpret_cast<const float4v*>(bPtr + (size_t)dk * NDIM);

    f32x4 acc[4][4];
#pragma unroll
    for (int i = 0; i < 4; ++i)
#pragma unroll
        for (int j = 0; j < 4; ++j) {
            acc[i][j][0] = 0.f; acc[i][j][1] = 0.f; acc[i][j][2] = 0.f; acc[i][j][3] = 0.f;
        }

    const int r16 = lane & 15, g8 = (lane >> 4) * 8;
    for (int kt = 0; kt < KDIM; kt += 32) {
#pragma unroll
        for (int p = 0; p < 4; ++p) {
            ushort4v v;
            v[0] = f2bf(aReg[p][0]); v[1] = f2bf(aReg[p][1]);
            v[2] = f2bf(aReg[p][2]); v[3] = f2bf(aReg[p][3]);
            *reinterpret_cast<ushort4v*>(&As[rA + 32 * p][kA]) = v;
        }
        unsigned short bb[4][4];
#pragma unroll
        for (int dk = 0; dk < 4; ++dk)
#pragma unroll
            for (int dn = 0; dn < 4; ++dn)
                bb[dn][dk] = (bReg[dk][dn] > 0.0f) ? (unsigned short)0x3F80u
                                                   : (unsigned short)0u;
#pragma unroll
        for (int dn = 0; dn < 4; ++dn) {
            ushort4v v;
            v[0] = bb[dn][0]; v[1] = bb[dn][1]; v[2] = bb[dn][2]; v[3] = bb[dn][3];
            *reinterpret_cast<ushort4v*>(&Bs[nB + dn][kB]) = v;
        }
        __syncthreads();
        if (kt + 32 < KDIM) {
#pragma unroll
            for (int p = 0; p < 4; ++p)
                aReg[p] = *reinterpret_cast<const float4v*>(
                    aPtr + (size_t)(32 * p) * KDIM + (kt + 32));
#pragma unroll
            for (int dk = 0; dk < 4; ++dk)
                bReg[dk] = *reinterpret_cast<const float4v*>(
                    bPtr + (size_t)(kt + 32 + dk) * NDIM);
        }
        short8 af[4], bfv[4];
#pragma unroll
        for (int mi = 0; mi < 4; ++mi)
            af[mi] = *reinterpret_cast<const short8*>(&As[wr * 64 + mi * 16 + r16][g8]);
#pragma unroll
        for (int ni = 0; ni < 4; ++ni)
            bfv[ni] = *reinterpret_cast<const short8*>(&Bs[wc * 64 + ni * 16 + r16][g8]);
#pragma unroll
        for (int mi = 0; mi < 4; ++mi)
#pragma unroll
            for (int ni = 0; ni < 4; ++ni)
                acc[mi][ni] = __builtin_amdgcn_mfma_f32_16x16x32_bf16(
                    af[mi], bfv[ni], acc[mi][ni], 0, 0, 0);
        __syncthreads();
    }

    const int orow0 = bm * 128 + wr * 64 + (lane >> 4) * 4;
    const int ocol0 = bn * 128 + wc * 64 + r16;
#pragma unroll
    for (int mi = 0; mi < 4; ++mi)
#pragma unroll
        for (int ni = 0; ni < 4; ++ni)
#pragma unroll
            for (int r = 0; r < 4; ++r)
                O[(size_t)(orow0 + mi * 16 + r) * NDIM + ocol0 + ni * 16] =
                    acc[mi][ni][r];
}

extern "C" void kernel_launch(void* const* d_in, const int* in_sizes, int n_in,
                              void* d_out, int out_size, void* d_ws, size_t ws_size,
                              hipStream_t stream) {
    const float* X = (const float*)d_in[0];
    const float* W = (const float*)d_in[1];
    float* O = (float*)d_out;
    (void)in_sizes; (void)n_in; (void)out_size;

    const size_t xq_bytes = (size_t)MDIM * KDIM;          // 16 MB
    const size_t wt_bytes = (size_t)NDIM * KDIM;          // 4 MB
    const size_t sc_bytes = (size_t)MDIM * sizeof(float); // 32 KB
    const size_t need = xq_bytes + wt_bytes + sc_bytes;

    if (ws_size >= need) {
        signed char* Xq = (signed char*)d_ws;
        signed char* Wt = Xq + xq_bytes;
        float* Sc = (float*)(Wt + wt_bytes);
        hipFuncSetAttribute((const void*)gemm_mb,
                            hipFuncAttributeMaxDynamicSharedMemorySize, 131072);
        prep<<<dim3(MDIM + (KDIM / 64) * (NDIM / 64)), dim3(256), 0, stream>>>(X, W, Xq, Wt, Sc);
        gemm_mb<<<dim3((MDIM / 256) * (NDIM / 256)), dim3(1024), 131072, stream>>>(Xq, Wt, Sc, O);
    } else {
        binlin_fused<<<dim3((MDIM / 128) * (NDIM / 128)), dim3(256), 0, stream>>>(X, W, O);
    }
}